// Round 18
// baseline (415.860 us; speedup 1.0000x reference)
//
#include <hip/hip_runtime.h>
#include <hip/hip_fp16.h>

typedef _Float16 f16;
typedef _Float16 f16x8 __attribute__((ext_vector_type(8)));
typedef _Float16 f16x4 __attribute__((ext_vector_type(4)));
typedef float f32x4 __attribute__((ext_vector_type(4)));
typedef float f32x16 __attribute__((ext_vector_type(16)));

#define GLB(p) ((const __attribute__((address_space(1))) void*)(p))
#define LDSP(p) ((__attribute__((address_space(3))) void*)(p))

__device__ __forceinline__ void gload16(const void* g, void* l) {
  __builtin_amdgcn_global_load_lds(GLB(g), LDSP(l), 16, 0, 0);
}

#define VMW(n) asm volatile("s_waitcnt vmcnt(" #n ")" ::: "memory")
__device__ __forceinline__ void barrier_fenced() {
  asm volatile("s_waitcnt lgkmcnt(0)" ::: "memory");
  __builtin_amdgcn_s_barrier();
  asm volatile("" ::: "memory");
}

// ---------------- xpose: x -> xb (f16 [t][c]) + xbT (f16 [bc][c][t]) ----------------
__global__ __launch_bounds__(256) void xpose(const float* __restrict__ x,
                                             f16* __restrict__ xb,
                                             f16* __restrict__ xbT) {
  __shared__ f16 t[32 * 268];
  const int tid = threadIdx.x;
  const int bc = blockIdx.x >> 3, tt = blockIdx.x & 7;
  const long tbase = (long)(bc * 256 + tt * 32);
#pragma unroll
  for (int i = 0; i < 8; ++i) {
    int tr = (tid >> 6) + i * 4;  // 0..31
    int c4 = (tid & 63) * 4;
    float4 v = *(const float4*)(x + (tbase + tr) * 256 + c4);
    f16x4 o = {(f16)v.x, (f16)v.y, (f16)v.z, (f16)v.w};
    *(f16x4*)(xb + (tbase + tr) * 256 + c4) = o;
    *(f16x4*)(&t[tr * 268 + c4]) = o;
  }
  __syncthreads();
#pragma unroll
  for (int i = 0; i < 8; ++i) {
    int c = (tid >> 3) + i * 32;  // 0..255
    int t0 = (tid & 7) * 4;       // 0..28
    f16x4 v;
#pragma unroll
    for (int j = 0; j < 4; ++j) v[j] = t[(t0 + j) * 268 + c];
    *(f16x4*)(&xbT[(long)bc * 65536 + (long)c * 256 + tt * 32 + t0]) = v;
  }
}

// ---------------- bfrag: row-major [r][256] -> fragment-major [g(32)][r][8] ------
__global__ __launch_bounds__(256) void bfrag(const f16* __restrict__ xb,
                                             const f16* __restrict__ xbT,
                                             f16* __restrict__ xBf,
                                             f16* __restrict__ xTf) {
  int g = blockIdx.x * 256 + threadIdx.x;  // 0..2097151
  const f16* in = (g < 1048576) ? xb : xbT;
  f16* out = (g < 1048576) ? xBf : xTf;
  int i = g & 1048575;
  int bc = i >> 13, rem = i & 8191;
  int r = rem >> 5, gg = rem & 31;
  f16x8 v = *(const f16x8*)(in + (long)bc * 65536 + r * 256 + gg * 8);
  *(f16x8*)(out + (long)bc * 65536 + gg * 2048 + r * 8) = v;
}

// ---------------- prep_w2: per-head K-innermost weights + permuted biases ----------
__global__ __launch_bounds__(256) void prep_w2(
    const float* __restrict__ Wq, const float* __restrict__ Wk,
    const float* __restrict__ Wv, const float* __restrict__ Wo,
    const float* __restrict__ bq, const float* __restrict__ bv,
    f16* __restrict__ WqT2, f16* __restrict__ WkT2, f16* __restrict__ WvT2,
    f16* __restrict__ WoT, float* __restrict__ bqp, float* __restrict__ bvp) {
  int g = blockIdx.x * 256 + threadIdx.x;  // 0..524287
  int hc = g >> 8, d = g & 255;
  int h = hc >> 8, c = hc & 255;
  int src = c * 2048 + d * 8 + h;
  WqT2[g] = (f16)Wq[src];
  WkT2[g] = (f16)Wk[src];
  WvT2[g] = (f16)Wv[src];
  int dm = g >> 11, np = g & 2047;
  WoT[g] = (f16)Wo[((np & 255) * 8 + (np >> 8)) * 256 + dm];
  if (g < 2048) {
    int s2 = (g & 255) * 8 + (g >> 8);
    bqp[g] = bq[s2];
    bvp[g] = bv[s2];
  }
}

// ---------------- gemm_pre: MTf_h, GTf_h (fragment-major) + wv + bo2 ----------
__global__ __launch_bounds__(256) void gemm_pre(
    const f16* __restrict__ WqT2, const f16* __restrict__ WkT2,
    const f16* __restrict__ WvT2, const f16* __restrict__ WoT,
    const float* __restrict__ bqp, const float* __restrict__ bvp,
    const float* __restrict__ bo, f16* __restrict__ MTf, f16* __restrict__ GTf,
    float* __restrict__ wv, float* __restrict__ bo2) {
  const int bid = blockIdx.x;
  if (bid >= 32) {
    if (bid == 32) {
      int c = threadIdx.x;
      for (int h = 0; h < 8; ++h) {
        const f16* row = WkT2 + ((h * 256 + c) << 8);
        float acc = 0.f;
        for (int d8 = 0; d8 < 32; ++d8) {
          f16x8 kv = *(const f16x8*)(row + d8 * 8);
#pragma unroll
          for (int e = 0; e < 8; ++e)
            acc += (float)kv[e] * bqp[h * 256 + d8 * 8 + e];
        }
        wv[h * 256 + c] = acc;
      }
    } else {
      int dm = threadIdx.x;
      const f16* row = WoT + dm * 2048;
      float acc = bo[dm];
      for (int n8 = 0; n8 < 256; ++n8) {
        f16x8 ov = *(const f16x8*)(row + n8 * 8);
#pragma unroll
        for (int e = 0; e < 8; ++e) acc += (float)ov[e] * bvp[n8 * 8 + e];
      }
      bo2[dm] = acc;
    }
    return;
  }
  __shared__ __align__(16) char smem[49152];  // A 2x8KB @0, B 2x16KB @16384
  const int mat = bid >> 4, h = (bid >> 1) & 7, mt = bid & 1;
  const f16* A;
  long As;
  const f16* B;
  f16* C;
  if (mat == 0) {
    A = WkT2 + h * 65536 + mt * 32768;
    As = 256;
    B = WqT2 + h * 65536;
    C = MTf + h * 65536;
  } else {
    A = WoT + h * 256 + (long)mt * 128 * 2048;
    As = 2048;
    B = WvT2 + h * 65536;
    C = GTf + h * 65536;
  }
  const int tid = threadIdx.x;
  const int lane = tid & 63, wid = tid >> 6;  // 4 waves
  const int l15 = lane & 15, lg = lane >> 4;
  const int w32 = wid * 32;

  auto stageA = [&](int ct) {
#pragma unroll
    for (int r = 0; r < 2; ++r) {
      int flat = r * 4096 + tid * 16;
      int row = flat >> 6;
      int kk = ct * 32 + (((flat ^ (((row >> 1) & 3) << 4)) & 63) >> 1);
      gload16(A + (long)row * As + kk, smem + (ct & 1) * 8192 + flat);
    }
  };
  auto stageB = [&](int ct) {
#pragma unroll
    for (int r = 0; r < 4; ++r) {
      int flat = r * 4096 + tid * 16;
      int row = flat >> 6;
      int kk = ct * 32 + (((flat ^ (((row >> 1) & 3) << 4)) & 63) >> 1);
      gload16(B + (long)row * 256 + kk, smem + 16384 + (ct & 1) * 16384 + flat);
    }
  };
  auto ldA = [&](int ct, int row) -> f16x8 {
    return *(const f16x8*)(smem + (ct & 1) * 8192 + row * 64 +
                           ((lg * 16) ^ (((row >> 1) & 3) << 4)));
  };
  auto ldB = [&](int ct, int row) -> f16x8 {
    return *(const f16x8*)(smem + 16384 + (ct & 1) * 16384 + row * 64 +
                           ((lg * 16) ^ (((row >> 1) & 3) << 4)));
  };

  f32x4 acc[2][16] = {};
  stageA(0);
  stageB(0);
  for (int ct = 0; ct < 8; ++ct) {
    VMW(0);
    barrier_fenced();
    if (ct < 7) {
      stageA(ct + 1);
      stageB(ct + 1);
    }
    f16x8 af[2];
#pragma unroll
    for (int i = 0; i < 2; ++i) af[i] = ldA(ct, w32 + i * 16 + l15);
#pragma unroll
    for (int f = 0; f < 16; ++f) {
      f16x8 bf = ldB(ct, f * 16 + l15);
#pragma unroll
      for (int i = 0; i < 2; ++i)
        acc[i][f] = __builtin_amdgcn_mfma_f32_16x16x32_f16(af[i], bf, acc[i][f], 0, 0, 0);
    }
  }
  // fragment-major epilogue: dst = (n>>3)*2048 + (mt*128+m)*8 + (n&7)
#pragma unroll
  for (int i = 0; i < 2; ++i)
#pragma unroll
    for (int f = 0; f < 16; ++f)
#pragma unroll
      for (int jj = 0; jj < 4; ++jj) {
        int m = mt * 128 + w32 + i * 16 + lg * 4 + jj;
        int n = f * 16 + l15;
        C[(n >> 3) * 2048 + m * 8 + (n & 7)] = (f16)acc[i][f][jj];
      }
}

// ---------------- vcomp: v[bc][h][j] = sum_c xb[bc][j][c] * wv[h][c] ----------------
__global__ __launch_bounds__(256) void vcomp(const f16* __restrict__ xb,
                                             const float* __restrict__ wv,
                                             float* __restrict__ v) {
  __shared__ float wl[2048];
  const int bc = blockIdx.x, tid = threadIdx.x;
  for (int r = 0; r < 8; ++r) wl[r * 256 + tid] = wv[r * 256 + tid];
  __syncthreads();
  const f16* row = xb + (long)bc * 65536 + (long)tid * 256;
  float a[8] = {};
  for (int c8 = 0; c8 < 32; ++c8) {
    f16x8 xv = *(const f16x8*)(row + c8 * 8);
#pragma unroll
    for (int h = 0; h < 8; ++h) {
      float s = 0.f;
#pragma unroll
      for (int e = 0; e < 8; ++e) s += (float)xv[e] * wl[h * 256 + c8 * 8 + e];
      a[h] += s;
    }
  }
  for (int h = 0; h < 8; ++h) v[bc * 2048 + h * 256 + tid] = a[h];
}

// ---------------- attn_fused12: barrier-free, 8 col-slices, distance-2 prefetch ----
// Block (bc, qt, h): 128 q rows. 8 waves = 8 col-slices (wid = cq, 32 cols);
// per-wave output 128 rows x 32 cols -> acc[4] f32x16 = 64 regs.
// Per iteration: ONE B fragment load (fragment-major, contiguous 512B/half-wave,
// L2-hot) prefetched at distance 2 (2 iters x ~128cy wall at 4 waves/SIMD
// ~= 256cy cover >= L2 latency), 4 A LDS reads (conflict-free swizzle), 4 MFMA.
// A region [128][512B]: xA -> T -> P -> R in place; barriers at phase bounds only.
__global__ __launch_bounds__(512, 2) void attn_fused12(
    const f16* __restrict__ xb, const f16* __restrict__ xBf,
    const f16* __restrict__ xTf, const f16* __restrict__ MTf,
    const f16* __restrict__ GTf, const float* __restrict__ vw,
    f16* __restrict__ Zp) {
  __shared__ __align__(16) char smem[65536];
  const int tid = threadIdx.x;
  const int lane = tid & 63, wid = tid >> 6;  // wid = col slice (0..7)
  const int l31 = lane & 31, lh = lane >> 5;
  const int bc = blockIdx.x, qt = blockIdx.y, h = blockIdx.z;
  const f16* xA = xb + (long)bc * 65536 + (long)qt * 32768;  // 128 rows row-major
  const f16* xBfb = xBf + (long)bc * 65536;
  const f16* xTfb = xTf + (long)bc * 65536;
  const f16* MTh = MTf + h * 65536;
  const f16* GTh = GTf + h * 65536;

  const float vv = vw[bc * 2048 + h * 256 + wid * 32 + l31];

  // xA -> region, linear dest, pre-swizzled source
  auto stageX = [&]() {
#pragma unroll
    for (int i = 0; i < 8; ++i) {
      int flat = i * 8192 + tid * 16;
      int row = flat >> 9;
      int cb = (flat & 511) ^ ((row & 31) << 4);
      gload16(xA + (long)row * 256 + (cb >> 1), smem + flat);
    }
  };
  auto ldA = [&](int rt, int kt) -> f16x8 {
    int row = rt * 32 + l31;
    return *(const f16x8*)(smem + row * 512 +
                           ((kt * 32 + lh * 16) ^ ((row & 31) << 4)));
  };
  auto st0 = [&](int row, int col, f16 v_) {
    *(f16*)(smem + row * 512 + ((col * 2) ^ ((row & 31) << 4))) = v_;
  };

  f32x16 acc[4];
  auto zacc = [&]() {
#pragma unroll
    for (int i = 0; i < 4; ++i) acc[i] = (f32x16)(0.f);
  };
  // one full K=256 phase: A from region, B fragment-major from global,
  // ONE B load per iter, register prefetch distance 2 (static kt&1 index)
  auto phase = [&](const f16* Bf) {
    const f16* p0 = Bf + ((long)lh * 2048 + (wid * 32 + l31) * 8);  // kt stride 4096
    f16x8 pb0 = *(const f16x8*)(p0);
    f16x8 pb1 = *(const f16x8*)(p0 + 4096);
#pragma unroll
    for (int kt = 0; kt < 16; ++kt) {
      f16x8 b = (kt & 1) ? pb1 : pb0;
      if (kt + 2 < 16) {
        if (kt & 1)
          pb1 = *(const f16x8*)(p0 + (kt + 2) * 4096);
        else
          pb0 = *(const f16x8*)(p0 + (kt + 2) * 4096);
      }
#pragma unroll
      for (int rt = 0; rt < 4; ++rt) {
        f16x8 a = ldA(rt, kt);
        acc[rt] = __builtin_amdgcn_mfma_f32_32x32x16_f16(a, b, acc[rt], 0, 0, 0);
      }
    }
  };
  // write acc to region (C layout row=rt*32+(r&3)+8*(r>>2)+4*lh, col=wid*32+l31)
  auto wr0 = [&]() {
#pragma unroll
    for (int rt = 0; rt < 4; ++rt)
#pragma unroll
      for (int r = 0; r < 16; ++r)
        st0(rt * 32 + (r & 3) + 8 * (r >> 2) + 4 * lh, wid * 32 + l31,
            (f16)acc[rt][r]);
  };

  // prologue: xA into region
  stageX();
  VMW(0);
  barrier_fenced();

  // ---- phase T: T = xA * MT^T ----
  zacc();
  phase(MTh);
  barrier_fenced();  // all xA LDS reads done
  wr0();             // T over xA
  barrier_fenced();

  // ---- phase S: S = T * xB^T ----
  zacc();
  phase(xBfb);
  barrier_fenced();  // all T reads done (T dead; stats may use region head)

  // ---- softmax across 8 col-slices (stats in dead region rows 0..15) ----
  {
    float* mb = (float*)smem;           // [8][128]
    float* lb = (float*)(smem + 4096);  // [8][128]
    const float SCL = 0.0625f * 1.44269504089f;
#pragma unroll
    for (int rt = 0; rt < 4; ++rt)
#pragma unroll
      for (int r = 0; r < 16; ++r) {
        int row = rt * 32 + (r & 3) + 8 * (r >> 2) + 4 * lh;
        float pm = acc[rt][r] + vv;
#pragma unroll
        for (int off = 1; off < 32; off <<= 1)
          pm = fmaxf(pm, __shfl_xor(pm, off, 64));
        if (l31 == 0) mb[wid * 128 + row] = pm;
      }
    barrier_fenced();
#pragma unroll
    for (int rt = 0; rt < 4; ++rt)
#pragma unroll
      for (int r = 0; r < 16; ++r) {
        int row = rt * 32 + (r & 3) + 8 * (r >> 2) + 4 * lh;
        float m = mb[row];
#pragma unroll
        for (int w = 1; w < 8; ++w) m = fmaxf(m, mb[w * 128 + row]);
        float e = __builtin_exp2f((acc[rt][r] + vv - m) * SCL);
        acc[rt][r] = e;
        float s_ = e;
#pragma unroll
        for (int off = 1; off < 32; off <<= 1) s_ += __shfl_xor(s_, off, 64);
        if (l31 == 0) lb[wid * 128 + row] = s_;
      }
    barrier_fenced();
#pragma unroll
    for (int rt = 0; rt < 4; ++rt)
#pragma unroll
      for (int r = 0; r < 16; ++r) {
        int row = rt * 32 + (r & 3) + 8 * (r >> 2) + 4 * lh;
        float s_ = lb[row];
#pragma unroll
        for (int w = 1; w < 8; ++w) s_ += lb[w * 128 + row];
        acc[rt][r] *= 1.f / s_;
      }
    barrier_fenced();  // stats reads done before P overwrites rows 0..15
  }
  wr0();  // P -> region
  barrier_fenced();

  // ---- phase R: R = P * x (B = xTf) ----
  zacc();
  phase(xTfb);
  barrier_fenced();  // all P reads done
  wr0();             // R -> region
  barrier_fenced();

  // ---- phase Z: Z = R * GT^T ----
  zacc();
  phase(GTh);

  // write Z partial: Zp[bc][t][h*256+dm]
  const long zb = (long)bc * 524288 + (long)(qt * 128) * 2048 + h * 256;
#pragma unroll
  for (int rt = 0; rt < 4; ++rt)
#pragma unroll
    for (int r = 0; r < 16; ++r) {
      int trow = rt * 32 + (r & 3) + 8 * (r >> 2) + 4 * lh;
      int dm = wid * 32 + l31;
      Zp[zb + (long)trow * 2048 + dm] = (f16)acc[rt][r];
    }
}

// ---------------- reduce2: out = sum_h Zp + bo2 ----------------
__global__ __launch_bounds__(256) void reduce2(const f16* __restrict__ Zp,
                                               const float* __restrict__ bo2,
                                               float* __restrict__ out) {
  int g = blockIdx.x * 256 + threadIdx.x;  // 4096 blocks
  int flat = g * 4;                        // 4,194,304 f32 output
  int dm = flat & 255;
  int t = (flat >> 8) & 255;
  int bc = flat >> 16;  // 0..63
  const f16* zp = Zp + (long)bc * 524288 + (long)t * 2048 + dm;
  float4 s = *(const float4*)(bo2 + dm);
#pragma unroll
  for (int h = 0; h < 8; ++h) {
    f16x4 zv = *(const f16x4*)(zp + h * 256);
    s.x += (float)zv[0];
    s.y += (float)zv[1];
    s.z += (float)zv[2];
    s.w += (float)zv[3];
  }
  *(float4*)(out + flat) = s;
}

// ---------------- launch ----------------
// ws layout (bytes):
//   xb    @ 0         8388608    f16 [16384 tok][256 c]
//   xbT   @ 8388608   8388608    f16 [bc][256 c][256 t]
//   WqT2  @ 16777216  1048576    f16 [h*256+c][256 d]
//   WkT2  @ 17825792  1048576
//   WvT2  @ 18874368  1048576
//   WoT   @ 19922944  1048576    f16 [dm][h*256+d]
//   bqp   @ 20971520  8192       f32 [h*256+d]
//   bvp   @ 20979712  8192
//   MTf   @ 20987904  1048576    f16 fragment-major [h][g32][c'][8]
//   GTf   @ 22036480  1048576    f16 fragment-major [h][g32][dm][8]
//   wv    @ 23085056  8192       f32 [h][c]
//   bo2   @ 23093248  1024       f32 [dm]
//   v     @ 23094272  524288     f32 [bc][h][j]
//   Zp    @ 23618560  67108864   f16 [bc][t][h*256+dm]
//   xBf   @ 90727424  8388608    f16 fragment-major [bc][g32][t][8]
//   xTf   @ 99116032  8388608    f16 fragment-major [bc][g32][c][8]
extern "C" void kernel_launch(void* const* d_in, const int* in_sizes, int n_in,
                              void* d_out, int out_size, void* d_ws,
                              size_t ws_size, hipStream_t stream) {
  const float* x = (const float*)d_in[0];
  const float* Wq = (const float*)d_in[1];
  const float* bq = (const float*)d_in[2];
  const float* Wk = (const float*)d_in[3];
  const float* Wv = (const float*)d_in[5];
  const float* bv = (const float*)d_in[6];
  const float* Wo = (const float*)d_in[7];
  const float* bo = (const float*)d_in[8];

  char* ws = (char*)d_ws;
  f16* xb = (f16*)(ws + 0);
  f16* xbT = (f16*)(ws + 8388608);
  f16* WqT2 = (f16*)(ws + 16777216);
  f16* WkT2 = (f16*)(ws + 17825792);
  f16* WvT2 = (f16*)(ws + 18874368);
  f16* WoT = (f16*)(ws + 19922944);
  float* bqp = (float*)(ws + 20971520);
  float* bvp = (float*)(ws + 20979712);
  f16* MTf = (f16*)(ws + 20987904);
  f16* GTf = (f16*)(ws + 22036480);
  float* wvv = (float*)(ws + 23085056);
  float* bo2 = (float*)(ws + 23093248);
  float* vws = (float*)(ws + 23094272);
  f16* Zp = (f16*)(ws + 23618560);
  f16* xBf = (f16*)(ws + 90727424);
  f16* xTf = (f16*)(ws + 99116032);
  if (ws_size < 99116032ull + 8388608ull) return;  // ~103MB

  xpose<<<512, 256, 0, stream>>>(x, xb, xbT);
  prep_w2<<<2048, 256, 0, stream>>>(Wq, Wk, Wv, Wo, bq, bv, WqT2, WkT2, WvT2,
                                    WoT, bqp, bvp);
  gemm_pre<<<34, 256, 0, stream>>>(WqT2, WkT2, WvT2, WoT, bqp, bvp, bo, MTf,
                                   GTf, wvv, bo2);
  bfrag<<<8192, 256, 0, stream>>>(xb, xbT, xBf, xTf);
  vcomp<<<64, 256, 0, stream>>>(xb, wvv, vws);
  // grid (bc, qt, h): linear id = bc + 64*qt + 128*h -> id%8 = bc%8:
  // all 16 blocks of a bc land on one XCD (B operands L2-resident)
  attn_fused12<<<dim3(64, 2, 8), 512, 0, stream>>>(xb, xBf, xTf, MTf, GTf, vws,
                                                   Zp);
  reduce2<<<4096, 256, 0, stream>>>(Zp, bo2, (float*)d_out);
}

// Round 19
// 208.138 us; speedup vs baseline: 1.9980x; 1.9980x over previous
//
#include <hip/hip_runtime.h>
#include <hip/hip_fp16.h>

typedef _Float16 f16;
typedef _Float16 f16x8 __attribute__((ext_vector_type(8)));
typedef _Float16 f16x4 __attribute__((ext_vector_type(4)));
typedef float f32x4 __attribute__((ext_vector_type(4)));

#define GLB(p) ((const __attribute__((address_space(1))) void*)(p))
#define LDSP(p) ((__attribute__((address_space(3))) void*)(p))

__device__ __forceinline__ void gload16(const void* g, void* l) {
  __builtin_amdgcn_global_load_lds(GLB(g), LDSP(l), 16, 0, 0);
}

#define VMW(n) asm volatile("s_waitcnt vmcnt(" #n ")" ::: "memory")
__device__ __forceinline__ void barrier_fenced() {
  asm volatile("" ::: "memory");
  __builtin_amdgcn_s_barrier();
  asm volatile("" ::: "memory");
}

// ---------------- xpose: x -> xb (f16 [t][c]) + xbT (f16 [bc][c][t]) ----------------
// 512 blocks = 64 bc x 8 tt; tile [32 t][256 c]; LDS transpose, 8B writes.
__global__ __launch_bounds__(256) void xpose(const float* __restrict__ x,
                                             f16* __restrict__ xb,
                                             f16* __restrict__ xbT) {
  __shared__ f16 t[32 * 268];
  const int tid = threadIdx.x;
  const int bc = blockIdx.x >> 3, tt = blockIdx.x & 7;
  const long tbase = (long)(bc * 256 + tt * 32);
#pragma unroll
  for (int i = 0; i < 8; ++i) {
    int tr = (tid >> 6) + i * 4;  // 0..31
    int c4 = (tid & 63) * 4;
    float4 v = *(const float4*)(x + (tbase + tr) * 256 + c4);
    f16x4 o = {(f16)v.x, (f16)v.y, (f16)v.z, (f16)v.w};
    *(f16x4*)(xb + (tbase + tr) * 256 + c4) = o;
    *(f16x4*)(&t[tr * 268 + c4]) = o;
  }
  __syncthreads();
#pragma unroll
  for (int i = 0; i < 8; ++i) {
    int c = (tid >> 3) + i * 32;  // 0..255
    int t0 = (tid & 7) * 4;       // 0..28
    f16x4 v;
#pragma unroll
    for (int j = 0; j < 4; ++j) v[j] = t[(t0 + j) * 268 + c];
    *(f16x4*)(&xbT[(long)bc * 65536 + (long)c * 256 + tt * 32 + t0]) = v;
  }
}

// ---------------- prep_w2: per-head K-innermost weights + permuted biases ----------
// WqT2/WkT2/WvT2[h*256+c][d] = W[c][d*8+h]; WoT[dm][h*256+d] = Wo[(d*8+h)][dm]
__global__ __launch_bounds__(256) void prep_w2(
    const float* __restrict__ Wq, const float* __restrict__ Wk,
    const float* __restrict__ Wv, const float* __restrict__ Wo,
    const float* __restrict__ bq, const float* __restrict__ bv,
    f16* __restrict__ WqT2, f16* __restrict__ WkT2, f16* __restrict__ WvT2,
    f16* __restrict__ WoT, float* __restrict__ bqp, float* __restrict__ bvp) {
  int g = blockIdx.x * 256 + threadIdx.x;  // 0..524287
  int hc = g >> 8, d = g & 255;
  int h = hc >> 8, c = hc & 255;
  int src = c * 2048 + d * 8 + h;
  WqT2[g] = (f16)Wq[src];
  WkT2[g] = (f16)Wk[src];
  WvT2[g] = (f16)Wv[src];
  int dm = g >> 11, np = g & 2047;
  WoT[g] = (f16)Wo[((np & 255) * 8 + (np >> 8)) * 256 + dm];
  if (g < 2048) {
    int s2 = (g & 255) * 8 + (g >> 8);
    bqp[g] = bq[s2];
    bvp[g] = bv[s2];
  }
}

// ---------------- gemm_pre: MT_h, GT_h (128x256 tiles, K=256) + wv + bo2 ----------
// blocks 0..31: D[m][n] = sum_k A[m*As+k]*B[n*256+k] -> C[m*256+n] f16
//   mat0 (MT): MT_h[c'][c] = sum_d Wk_h[c'][d]*Wq_h[c][d]
//   mat1 (GT): GT_h[dm][c] = sum_d Wo_h[d][dm]*Wv_h[c][d]
// block 32: wv[h*256+c] = sum_d WkT2[h256+c][d]*bqp[h256+d]
// block 33: bo2[dm] = bo[dm] + sum_np WoT[dm][np]*bvp[np]
__global__ __launch_bounds__(256) void gemm_pre(
    const f16* __restrict__ WqT2, const f16* __restrict__ WkT2,
    const f16* __restrict__ WvT2, const f16* __restrict__ WoT,
    const float* __restrict__ bqp, const float* __restrict__ bvp,
    const float* __restrict__ bo, f16* __restrict__ MT, f16* __restrict__ GT,
    float* __restrict__ wv, float* __restrict__ bo2) {
  const int bid = blockIdx.x;
  if (bid >= 32) {
    if (bid == 32) {
      int c = threadIdx.x;
      for (int h = 0; h < 8; ++h) {
        const f16* row = WkT2 + ((h * 256 + c) << 8);
        float acc = 0.f;
        for (int d8 = 0; d8 < 32; ++d8) {
          f16x8 kv = *(const f16x8*)(row + d8 * 8);
#pragma unroll
          for (int e = 0; e < 8; ++e)
            acc += (float)kv[e] * bqp[h * 256 + d8 * 8 + e];
        }
        wv[h * 256 + c] = acc;
      }
    } else {
      int dm = threadIdx.x;
      const f16* row = WoT + dm * 2048;
      float acc = bo[dm];
      for (int n8 = 0; n8 < 256; ++n8) {
        f16x8 ov = *(const f16x8*)(row + n8 * 8);
#pragma unroll
        for (int e = 0; e < 8; ++e) acc += (float)ov[e] * bvp[n8 * 8 + e];
      }
      bo2[dm] = acc;
    }
    return;
  }
  __shared__ __align__(16) char smem[49152];  // A 2x8KB @0, B 2x16KB @16384
  const int mat = bid >> 4, h = (bid >> 1) & 7, mt = bid & 1;
  const f16* A;
  long As;
  const f16* B;
  f16* C;
  if (mat == 0) {
    A = WkT2 + h * 65536 + mt * 32768;
    As = 256;
    B = WqT2 + h * 65536;
    C = MT + h * 65536 + mt * 32768;
  } else {
    A = WoT + h * 256 + (long)mt * 128 * 2048;
    As = 2048;
    B = WvT2 + h * 65536;
    C = GT + h * 65536 + mt * 32768;
  }
  const int tid = threadIdx.x;
  const int lane = tid & 63, wid = tid >> 6;  // 4 waves
  const int l15 = lane & 15, lg = lane >> 4;
  const int w32 = wid * 32;

  auto stageA = [&](int ct) {
#pragma unroll
    for (int r = 0; r < 2; ++r) {
      int flat = r * 4096 + tid * 16;
      int row = flat >> 6;
      int kk = ct * 32 + (((flat ^ (((row >> 1) & 3) << 4)) & 63) >> 1);
      gload16(A + (long)row * As + kk, smem + (ct & 1) * 8192 + flat);
    }
  };
  auto stageB = [&](int ct) {
#pragma unroll
    for (int r = 0; r < 4; ++r) {
      int flat = r * 4096 + tid * 16;
      int row = flat >> 6;
      int kk = ct * 32 + (((flat ^ (((row >> 1) & 3) << 4)) & 63) >> 1);
      gload16(B + (long)row * 256 + kk, smem + 16384 + (ct & 1) * 16384 + flat);
    }
  };
  auto ldA = [&](int ct, int row) -> f16x8 {
    return *(const f16x8*)(smem + (ct & 1) * 8192 + row * 64 +
                           ((lg * 16) ^ (((row >> 1) & 3) << 4)));
  };
  auto ldB = [&](int ct, int row) -> f16x8 {
    return *(const f16x8*)(smem + 16384 + (ct & 1) * 16384 + row * 64 +
                           ((lg * 16) ^ (((row >> 1) & 3) << 4)));
  };

  f32x4 acc[2][16] = {};
  stageA(0);
  stageB(0);
  for (int ct = 0; ct < 8; ++ct) {
    VMW(0);
    barrier_fenced();
    if (ct < 7) {
      stageA(ct + 1);
      stageB(ct + 1);
    }
    f16x8 af[2];
#pragma unroll
    for (int i = 0; i < 2; ++i) af[i] = ldA(ct, w32 + i * 16 + l15);
#pragma unroll
    for (int f = 0; f < 16; ++f) {
      f16x8 bf = ldB(ct, f * 16 + l15);
#pragma unroll
      for (int i = 0; i < 2; ++i)
        acc[i][f] = __builtin_amdgcn_mfma_f32_16x16x32_f16(af[i], bf, acc[i][f], 0, 0, 0);
    }
  }
#pragma unroll
  for (int i = 0; i < 2; ++i)
#pragma unroll
    for (int f = 0; f < 16; ++f)
#pragma unroll
      for (int jj = 0; jj < 4; ++jj)
        C[(w32 + i * 16 + lg * 4 + jj) * 256 + f * 16 + l15] = (f16)acc[i][f][jj];
}

// ---------------- vcomp: v[bc][h][j] = sum_c xb[bc][j][c] * wv[h][c] ----------------
__global__ __launch_bounds__(256) void vcomp(const f16* __restrict__ xb,
                                             const float* __restrict__ wv,
                                             float* __restrict__ v) {
  __shared__ float wl[2048];
  const int bc = blockIdx.x, tid = threadIdx.x;
  for (int r = 0; r < 8; ++r) wl[r * 256 + tid] = wv[r * 256 + tid];
  __syncthreads();
  const f16* row = xb + (long)bc * 65536 + (long)tid * 256;
  float a[8] = {};
  for (int c8 = 0; c8 < 32; ++c8) {
    f16x8 xv = *(const f16x8*)(row + c8 * 8);
#pragma unroll
    for (int h = 0; h < 8; ++h) {
      float s = 0.f;
#pragma unroll
      for (int e = 0; e < 8; ++e) s += (float)xv[e] * wl[h * 256 + c8 * 8 + e];
      a[h] += s;
    }
  }
  for (int h = 0; h < 8; ++h) v[bc * 2048 + h * 256 + tid] = a[h];
}

// ---------------- attn_fused6 (round-11 verified: 125us, VGPR 100, no spill) ----
// Block (bc, qt, h): 128 q rows. Phases (each = streamed-B 16x{8KB tile, 8 MFMA}):
//   T = xA * MT^T ; S = T * xB^T (+v, softmax -> P) ; R = P * xT^T ; Z = R * GT^T
// region0 @0 64KB: phase-T A-bufs then T -> P -> R (f16 [128][256], swizzle,
// wave-private rows). B-stream @65536 2x8KB. LDS 80KB -> 2 blocks/CU.
__global__ __launch_bounds__(512, 2) void attn_fused6(
    const f16* __restrict__ xb, const f16* __restrict__ xbT,
    const f16* __restrict__ MT, const f16* __restrict__ GT,
    const float* __restrict__ vw, f16* __restrict__ Zp) {
  __shared__ __align__(16) char smem[81920];
  const int tid = threadIdx.x;
  const int lane = tid & 63, wid = tid >> 6;  // 8 waves x 16 rows
  const int l15 = lane & 15, lg = lane >> 4;
  const int w16 = wid * 16;
  const int bc = blockIdx.x, qt = blockIdx.y, h = blockIdx.z;
  const f16* xB = xb + (long)bc * 65536;   // [t][c]
  const f16* xA = xB + qt * 32768;         // this block's 128 q rows
  const f16* xT = xbT + (long)bc * 65536;  // [c][t]
  const f16* MTh = MT + h * 65536;         // [c'][c]
  const f16* GTh = GT + h * 65536;         // [dm][c]

  // v for this lane's 16 j-columns (j = h2*128 + f*16 + l15)
  float vv[2][8];
  {
    const float* vb = vw + bc * 2048 + h * 256;
#pragma unroll
    for (int h2 = 0; h2 < 2; ++h2)
#pragma unroll
      for (int f = 0; f < 8; ++f) vv[h2][f] = vb[h2 * 128 + f * 16 + l15];
  }

  auto stageB8 = [&](const f16* src, int s) {  // [128 rows][32 k] 8KB, 1 pass
    int flat = tid * 16;
    int row = flat >> 6;
    int kk = ((flat ^ (((row >> 1) & 3) << 4)) & 63) >> 1;
    gload16(src + (long)row * 256 + kk, smem + 65536 + (s & 1) * 8192 + flat);
  };
  auto ldB8 = [&](int s, int row) -> f16x8 {
    return *(const f16x8*)(smem + 65536 + (s & 1) * 8192 + row * 64 +
                           ((lg * 16) ^ (((row >> 1) & 3) << 4)));
  };
  auto stageA8 = [&](int ct) {  // xA tile [128][32] into region0 bufs
    int flat = tid * 16;
    int row = flat >> 6;
    int kk = ct * 32 + (((flat ^ (((row >> 1) & 3) << 4)) & 63) >> 1);
    gload16(xA + (long)row * 256 + kk, smem + (ct & 1) * 8192 + flat);
  };
  auto ldA8 = [&](int ct, int row) -> f16x8 {
    return *(const f16x8*)(smem + (ct & 1) * 8192 + row * 64 +
                           ((lg * 16) ^ (((row >> 1) & 3) << 4)));
  };
  // region0 f16 [128][256]: byte = row*512 + (col*2 ^ ((row&7)<<4))
  auto st0 = [&](int row, int col, f16 val) {
    *(f16*)(smem + row * 512 + ((col * 2) ^ ((row & 7) << 4))) = val;
  };
  auto ld0 = [&](int row, int kt) -> f16x8 {
    return *(const f16x8*)(smem + row * 512 +
                           ((kt * 64 + lg * 16) ^ ((row & 7) << 4)));
  };

  const int arow = w16 + l15;  // A-frag row (wave's 16 rows)
  f32x4 acc[2][8];

  // ---------- phase T ----------
#pragma unroll
  for (int a = 0; a < 2; ++a)
#pragma unroll
    for (int b = 0; b < 8; ++b) acc[a][b] = (f32x4)(0.f);
  stageA8(0);
  stageB8(MTh, 0);
#pragma unroll
  for (int s = 0; s < 16; ++s) {
    const int ct = s >> 1, h2 = s & 1;
    VMW(0);
    barrier_fenced();
    if (s < 15) {
      const int ns = s + 1;
      stageB8(MTh + (ns & 1) * 32768 + (ns >> 1) * 32, ns);
      if ((ns & 1) == 0) stageA8(ns >> 1);
    }
    f16x8 af = ldA8(ct, arow);
    __builtin_amdgcn_s_setprio(1);
#pragma unroll
    for (int f = 0; f < 8; ++f) {
      f16x8 bf = ldB8(s, f * 16 + l15);
      acc[h2][f] = __builtin_amdgcn_mfma_f32_16x16x32_f16(af, bf, acc[h2][f], 0, 0, 0);
    }
    __builtin_amdgcn_s_setprio(0);
  }
  barrier_fenced();  // all region0 A-buf + B-buf reads done
#pragma unroll
  for (int h2 = 0; h2 < 2; ++h2)
#pragma unroll
    for (int f = 0; f < 8; ++f)
#pragma unroll
      for (int jj = 0; jj < 4; ++jj)
        st0(w16 + lg * 4 + jj, h2 * 128 + f * 16 + l15, (f16)acc[h2][f][jj]);

  // ---------- phase S ----------
#pragma unroll
  for (int a = 0; a < 2; ++a)
#pragma unroll
    for (int b = 0; b < 8; ++b) acc[a][b] = (f32x4)(0.f);
  stageB8(xB, 0);
#pragma unroll
  for (int s = 0; s < 16; ++s) {
    const int ct = s >> 1, jh = s & 1;
    VMW(0);
    barrier_fenced();
    if (s < 15) {
      const int ns = s + 1;
      stageB8(xB + (ns & 1) * 32768 + (ns >> 1) * 32, ns);
    }
    f16x8 af = ld0(arow, ct);
    __builtin_amdgcn_s_setprio(1);
#pragma unroll
    for (int f = 0; f < 8; ++f) {
      f16x8 bf = ldB8(s, f * 16 + l15);
      acc[jh][f] = __builtin_amdgcn_mfma_f32_16x16x32_f16(af, bf, acc[jh][f], 0, 0, 0);
    }
    __builtin_amdgcn_s_setprio(0);
  }
  barrier_fenced();

  // ---------- softmax over 256 j (rows wave-private) ----------
  const float SCL = 0.0625f * 1.44269504089f;
  float inv[4];
#pragma unroll
  for (int jj = 0; jj < 4; ++jj) {
    float m_ = acc[0][0][jj] + vv[0][0];
#pragma unroll
    for (int h2 = 0; h2 < 2; ++h2)
#pragma unroll
      for (int f = 0; f < 8; ++f)
        m_ = fmaxf(m_, acc[h2][f][jj] + vv[h2][f]);
#pragma unroll
    for (int off = 1; off < 16; off <<= 1) m_ = fmaxf(m_, __shfl_xor(m_, off, 64));
    float s_ = 0.f;
#pragma unroll
    for (int h2 = 0; h2 < 2; ++h2)
#pragma unroll
      for (int f = 0; f < 8; ++f) {
        float e = __builtin_exp2f((acc[h2][f][jj] + vv[h2][f] - m_) * SCL);
        acc[h2][f][jj] = e;
        s_ += e;
      }
#pragma unroll
    for (int off = 1; off < 16; off <<= 1) s_ += __shfl_xor(s_, off, 64);
    inv[jj] = 1.f / s_;
  }
#pragma unroll
  for (int h2 = 0; h2 < 2; ++h2)
#pragma unroll
    for (int f = 0; f < 8; ++f)
#pragma unroll
      for (int jj = 0; jj < 4; ++jj)
        st0(w16 + lg * 4 + jj, h2 * 128 + f * 16 + l15,
            (f16)(acc[h2][f][jj] * inv[jj]));

  // ---------- phase R: R = P * x (B = xT tiles) ----------
#pragma unroll
  for (int a = 0; a < 2; ++a)
#pragma unroll
    for (int b = 0; b < 8; ++b) acc[a][b] = (f32x4)(0.f);
  stageB8(xT, 0);
#pragma unroll
  for (int s = 0; s < 16; ++s) {
    const int jt = s >> 1, ch = s & 1;
    VMW(0);
    barrier_fenced();
    if (s < 15) {
      const int ns = s + 1;
      stageB8(xT + (ns & 1) * 32768 + (ns >> 1) * 32, ns);
    }
    f16x8 af = ld0(arow, jt);
    __builtin_amdgcn_s_setprio(1);
#pragma unroll
    for (int f = 0; f < 8; ++f) {
      f16x8 bf = ldB8(s, f * 16 + l15);
      acc[ch][f] = __builtin_amdgcn_mfma_f32_16x16x32_f16(af, bf, acc[ch][f], 0, 0, 0);
    }
    __builtin_amdgcn_s_setprio(0);
  }
  barrier_fenced();
#pragma unroll
  for (int ch = 0; ch < 2; ++ch)
#pragma unroll
    for (int f = 0; f < 8; ++f)
#pragma unroll
      for (int jj = 0; jj < 4; ++jj)
        st0(w16 + lg * 4 + jj, ch * 128 + f * 16 + l15, (f16)acc[ch][f][jj]);

  // ---------- phase Z: Z = R * G (B = GT tiles) ----------
#pragma unroll
  for (int a = 0; a < 2; ++a)
#pragma unroll
    for (int b = 0; b < 8; ++b) acc[a][b] = (f32x4)(0.f);
  stageB8(GTh, 0);
#pragma unroll
  for (int s = 0; s < 16; ++s) {
    const int ct = s >> 1, dh = s & 1;
    VMW(0);
    barrier_fenced();
    if (s < 15) {
      const int ns = s + 1;
      stageB8(GTh + (ns & 1) * 32768 + (ns >> 1) * 32, ns);
    }
    f16x8 af = ld0(arow, ct);
    __builtin_amdgcn_s_setprio(1);
#pragma unroll
    for (int f = 0; f < 8; ++f) {
      f16x8 bf = ldB8(s, f * 16 + l15);
      acc[dh][f] = __builtin_amdgcn_mfma_f32_16x16x32_f16(af, bf, acc[dh][f], 0, 0, 0);
    }
    __builtin_amdgcn_s_setprio(0);
  }

  // ---------- write Z partial: Zp[bc][t][h*256+dm] f16 ----------
  const long zb = (long)bc * 524288 + (long)(qt * 128) * 2048 + h * 256;
#pragma unroll
  for (int dh = 0; dh < 2; ++dh)
#pragma unroll
    for (int f = 0; f < 8; ++f)
#pragma unroll
      for (int jj = 0; jj < 4; ++jj) {
        int trow = w16 + lg * 4 + jj;
        int dm = dh * 128 + f * 16 + l15;
        Zp[zb + (long)trow * 2048 + dm] = (f16)acc[dh][f][jj];
      }
}

// ---------------- reduce2: out = sum_h Zp + bo2 ----------------
__global__ __launch_bounds__(256) void reduce2(const f16* __restrict__ Zp,
                                               const float* __restrict__ bo2,
                                               float* __restrict__ out) {
  int g = blockIdx.x * 256 + threadIdx.x;  // 4096 blocks
  int flat = g * 4;                        // 4,194,304 f32 output
  int dm = flat & 255;
  int t = (flat >> 8) & 255;
  int bc = flat >> 16;  // 0..63
  const f16* zp = Zp + (long)bc * 524288 + (long)t * 2048 + dm;
  float4 s = *(const float4*)(bo2 + dm);
#pragma unroll
  for (int h = 0; h < 8; ++h) {
    f16x4 zv = *(const f16x4*)(zp + h * 256);
    s.x += (float)zv[0];
    s.y += (float)zv[1];
    s.z += (float)zv[2];
    s.w += (float)zv[3];
  }
  *(float4*)(out + flat) = s;
}

// ---------------- launch ----------------
// ws layout (bytes):
//   xb    @ 0         8388608    f16 [16384 tok][256 c]
//   xbT   @ 8388608   8388608    f16 [bc][256 c][256 t]
//   WqT2  @ 16777216  1048576    f16 [h*256+c][256 d]
//   WkT2  @ 17825792  1048576
//   WvT2  @ 18874368  1048576
//   WoT   @ 19922944  1048576    f16 [dm][h*256+d]
//   bqp   @ 20971520  8192       f32 [h*256+d]
//   bvp   @ 20979712  8192
//   MT    @ 20987904  1048576    f16 [h][c'][c]
//   GT    @ 22036480  1048576    f16 [h][dm][c]
//   wv    @ 23085056  8192       f32 [h][c]
//   bo2   @ 23093248  1024       f32 [dm]
//   v     @ 23094272  524288     f32 [bc][h][j]
//   Zp    @ 23618560  67108864   f16 [bc][t][h*256+dm]
extern "C" void kernel_launch(void* const* d_in, const int* in_sizes, int n_in,
                              void* d_out, int out_size, void* d_ws,
                              size_t ws_size, hipStream_t stream) {
  const float* x = (const float*)d_in[0];
  const float* Wq = (const float*)d_in[1];
  const float* bq = (const float*)d_in[2];
  const float* Wk = (const float*)d_in[3];
  const float* Wv = (const float*)d_in[5];
  const float* bv = (const float*)d_in[6];
  const float* Wo = (const float*)d_in[7];
  const float* bo = (const float*)d_in[8];

  char* ws = (char*)d_ws;
  f16* xb = (f16*)(ws + 0);
  f16* xbT = (f16*)(ws + 8388608);
  f16* WqT2 = (f16*)(ws + 16777216);
  f16* WkT2 = (f16*)(ws + 17825792);
  f16* WvT2 = (f16*)(ws + 18874368);
  f16* WoT = (f16*)(ws + 19922944);
  float* bqp = (float*)(ws + 20971520);
  float* bvp = (float*)(ws + 20979712);
  f16* MTws = (f16*)(ws + 20987904);
  f16* GTws = (f16*)(ws + 22036480);
  float* wvv = (float*)(ws + 23085056);
  float* bo2 = (float*)(ws + 23093248);
  float* vws = (float*)(ws + 23094272);
  f16* Zp = (f16*)(ws + 23618560);
  if (ws_size < 23618560ull + 67108864ull) return;  // ~87MB

  xpose<<<512, 256, 0, stream>>>(x, xb, xbT);
  prep_w2<<<2048, 256, 0, stream>>>(Wq, Wk, Wv, Wo, bq, bv, WqT2, WkT2, WvT2,
                                    WoT, bqp, bvp);
  gemm_pre<<<34, 256, 0, stream>>>(WqT2, WkT2, WvT2, WoT, bqp, bvp, bo, MTws,
                                   GTws, wvv, bo2);
  vcomp<<<64, 256, 0, stream>>>(xb, wvv, vws);
  // grid (bc, qt, h): same-bc blocks adjacent -> share XCD L2 for xB/xT
  attn_fused6<<<dim3(64, 2, 8), 512, 0, stream>>>(xb, xbT, MTws, GTws, vws, Zp);
  reduce2<<<4096, 256, 0, stream>>>(Zp, bo2, (float*)d_out);
}